// Round 10
// baseline (71.192 us; speedup 1.0000x reference)
//
#include <hip/hip_runtime.h>
#include <hip/hip_bf16.h>

// out[q] = min(|{r : dist(q,r) <= thr}|, 100) / 100   (top-k unnecessary:
// any distance <= thr is among the 100 smallest unless count > 100, which clamps)
//
// Q=4096, R=16384, D=128. hit <=> dot(q,r) >= 0.5|q|^2 + (0.5|r|^2 - 0.5 thr^2)
// dist: 32x32x16 MFMA, depth-3 LDS ring, counted vmcnt, 4 blocks/CU, and an
// XCD-aware blockIdx decode (T1): blocks on XCD x (= bid%8) share refs
// [x*2048, (x+1)*2048) -> per-XCD L2 working set ~1.5 MB (vs 4+ MB scattered;
// R9 showed scatter = 150 MB beyond-L2 fetch = L3-BW-bound at 64 us).

#define DIM   128
#define ROWB  256              // bytes per bf16 row
#define BM    256              // queries per block (4 waves x 64)
#define BN    32               // refs per round
#define NSEG  64               // segments along R (256 refs each)
#define NTM   16               // Q/BM tile rows

typedef __attribute__((ext_vector_type(8)))  short short8;
typedef __attribute__((ext_vector_type(16))) float f32x16;

#define VMCNT(n) asm volatile("s_waitcnt vmcnt(" #n ")" ::: "memory")

// ---------------- prep: bf16 cast, folded norms/bias, zero counts ----------
__global__ void prep_kernel(const float* __restrict__ qe, const float* __restrict__ re,
                            __hip_bfloat16* __restrict__ qb, __hip_bfloat16* __restrict__ rb,
                            float* __restrict__ qhalf, float* __restrict__ rbias,
                            float* __restrict__ counts, const float* __restrict__ thr_p,
                            int Q, int R) {
    const int wave = threadIdx.x >> 6;
    const int lane = threadIdx.x & 63;
    const int row = blockIdx.x * 4 + wave;
    if (row >= Q + R) return;
    const float* src;
    __hip_bfloat16* dst;
    if (row < Q) {
        src = qe + (size_t)row * DIM;
        dst = qb + (size_t)row * DIM;
        if (lane == 0) counts[row] = 0.0f;
    } else {
        src = re + (size_t)(row - Q) * DIM;
        dst = rb + (size_t)(row - Q) * DIM;
    }
    float2 v = ((const float2*)src)[lane];
    float s = v.x * v.x + v.y * v.y;
    __hip_bfloat162 b;
    b.x = __float2bfloat16(v.x);
    b.y = __float2bfloat16(v.y);
    ((__hip_bfloat162*)dst)[lane] = b;
    #pragma unroll
    for (int off = 32; off > 0; off >>= 1) s += __shfl_down(s, off);
    if (lane == 0) {
        if (row < Q) qhalf[row] = 0.5f * s;
        else {
            const float thr = *thr_p;
            rbias[row - Q] = (thr >= 0.0f) ? 0.5f * s - 0.5f * thr * thr : 1e30f;
        }
    }
}

// ---------------- main: 32x32x16 MFMA, depth-3 ring, XCD-local segs --------
__launch_bounds__(256, 4)
__global__ void dist_count_kernel(const __hip_bfloat16* __restrict__ qb,
                                  const __hip_bfloat16* __restrict__ rb,
                                  const float* __restrict__ qhalf,
                                  const float* __restrict__ rbias,
                                  float* __restrict__ counts,
                                  int Q, int R) {
    __shared__ short Bs[3][BN * DIM];          // 3 x 8KB ring

    const int tid  = threadIdx.x;
    const int lane = tid & 63;
    const int wave = tid >> 6;
    const int l31  = lane & 31;
    const int lhi  = lane >> 5;

    // XCD-aware decode (HW: block b -> XCD b%8). Blocks on one XCD share an
    // 8-seg slice of R; tileM varies fastest. Bijective on 8*16*8 = 1024.
    const int bid = blockIdx.x;
    const int segIdx = (bid & 7) * 8 + (bid >> 7);   // 0..63
    const int tileM  = (bid >> 3) & (NTM - 1);       // 0..15

    const int seg  = R / NSEG;                 // 256
    const int base = segIdx * seg;
    const int NT   = seg / BN;                 // 8
    const int qrow0 = tileM * BM + wave * 64;

    const char* qbc = (const char*)qb;
    const char* rbc = (const char*)rb;

    // stage one 32x128 bf16 tile (8KB): linear LDS dest, XOR-swizzle folded
    // into the GLOBAL source column (rule #21: both-sides-or-neither).
    auto stage = [&](int tt) {
        short* buf = Bs[tt % 3];
        #pragma unroll
        for (int j = 0; j < 2; ++j) {
            const int lds_byte = (wave * 2 + j) * 1024 + lane * 16;
            const int row = lds_byte >> 8;     // 0..31
            const int col = lds_byte & 255;
            const int src = (base + tt * BN + row) * ROWB + (col ^ ((row & 15) << 4));
            __builtin_amdgcn_global_load_lds(
                (const __attribute__((address_space(1))) unsigned int*)(rbc + src),
                (__attribute__((address_space(3))) unsigned int*)((char*)buf + lds_byte),
                16, 0, 0);
        }
    };

    // A fragments: 64 query rows x K=128 (32x32x16 layout: row=l31, k=lhi*8+j)
    short8 a[8][2];                            // 64 VGPR
    #pragma unroll
    for (int ks = 0; ks < 8; ++ks)
        #pragma unroll
        for (int mi = 0; mi < 2; ++mi)
            a[ks][mi] = *(const short8*)(qbc + (size_t)(qrow0 + mi * 32 + l31) * ROWB
                                         + ks * 32 + lhi * 16);

    // wave-level min of its 64 query half-norms (conservative screen bound)
    float minqh;
    {
        float mq = qhalf[qrow0 + lane];
        #pragma unroll
        for (int off = 32; off > 0; off >>= 1) mq = fminf(mq, __shfl_xor(mq, off));
        minqh = mq;
    }

    // per-tile rbias for this lane (8 rounds)
    float rbv[8];
    #pragma unroll
    for (int i = 0; i < 8; ++i) rbv[i] = rbias[base + i * BN + l31];

    stage(0);
    stage(1);
    VMCNT(2);                                  // tile 0's loads (mine) done

    for (int t = 0; t < NT; ++t) {
        __builtin_amdgcn_s_barrier();          // all waves' tile-t loads confirmed
        __builtin_amdgcn_sched_barrier(0);
        if (t + 2 < NT) stage(t + 2);          // slot (t+2)%3 free since round t-1

        const char* cur = (const char*)Bs[t % 3];
        f32x16 acc[2] = {};

        __builtin_amdgcn_s_setprio(1);
        #pragma unroll
        for (int ks = 0; ks < 8; ++ks) {
            const int cb = (ks * 32 + lhi * 16) ^ ((l31 & 15) << 4);
            const short8 b = *(const short8*)(cur + l31 * ROWB + cb);
            #pragma unroll
            for (int mi = 0; mi < 2; ++mi)
                acc[mi] = __builtin_amdgcn_mfma_f32_32x32x16_bf16(a[ks][mi], b, acc[mi], 0, 0, 0);
        }
        __builtin_amdgcn_s_setprio(0);

        // ---- screened epilogue ----
        const float rb_t = rbv[t];
        float mx = fmaxf(acc[0][0], acc[1][0]);
        #pragma unroll
        for (int r = 1; r < 16; ++r) mx = fmaxf(mx, fmaxf(acc[0][r], acc[1][r]));

        if (__any(mx >= minqh + rb_t)) {       // rare slow path (generic-correct)
            #pragma unroll
            for (int mi = 0; mi < 2; ++mi)
                #pragma unroll
                for (int reg = 0; reg < 16; ++reg) {
                    // 32x32 C layout: row = (reg&3) + 8*(reg>>2) + 4*lhi
                    const int row = qrow0 + mi * 32 + (reg & 3) + 8 * (reg >> 2) + 4 * lhi;
                    float cnt = (acc[mi][reg] >= qhalf[row] + rb_t) ? 1.0f : 0.0f;
                    cnt += __shfl_xor(cnt, 1);
                    cnt += __shfl_xor(cnt, 2);
                    cnt += __shfl_xor(cnt, 4);
                    cnt += __shfl_xor(cnt, 8);
                    cnt += __shfl_xor(cnt, 16);
                    if (l31 == 0 && cnt != 0.0f)
                        atomicAdd(&counts[row], cnt);
                }
        }

        if (t + 2 < NT) { VMCNT(2); }          // tile t+1 resident; t+2 in flight
        else            { VMCNT(0); }
    }
}

// ---------------- finalize ----------------
__global__ void finalize_kernel(const float* __restrict__ counts,
                                float* __restrict__ out, int Q, int R) {
    int q = blockIdx.x * blockDim.x + threadIdx.x;
    if (q < Q) {
        float k = (R < 100) ? (float)R : 100.0f;
        out[q] = fminf(counts[q], k) / k;
    }
}

extern "C" void kernel_launch(void* const* d_in, const int* in_sizes, int n_in,
                              void* d_out, int out_size, void* d_ws, size_t ws_size,
                              hipStream_t stream) {
    const float* qe  = (const float*)d_in[0];
    const float* re  = (const float*)d_in[1];
    const float* thr = (const float*)d_in[2];
    float* out = (float*)d_out;

    const int Q = in_sizes[0] / DIM;   // 4096
    const int R = in_sizes[1] / DIM;   // 16384

    char* ws = (char*)d_ws;
    __hip_bfloat16* qb = (__hip_bfloat16*)ws;
    __hip_bfloat16* rb = (__hip_bfloat16*)(ws + (size_t)Q * DIM * 2);
    float* qhalf  = (float*)(ws + (size_t)(Q + R) * DIM * 2);
    float* rbias  = qhalf + Q;
    float* counts = rbias + R;

    const int rows = Q + R;
    prep_kernel<<<(rows + 3) / 4, 256, 0, stream>>>(qe, re, qb, rb, qhalf, rbias,
                                                    counts, thr, Q, R);

    dist_count_kernel<<<NSEG * NTM, 256, 0, stream>>>(qb, rb, qhalf, rbias, counts, Q, R);

    finalize_kernel<<<(Q + 255) / 256, 256, 0, stream>>>(counts, out, Q, R);
}

// Round 11
// 71.073 us; speedup vs baseline: 1.0017x; 1.0017x over previous
//
#include <hip/hip_runtime.h>
#include <hip/hip_bf16.h>

// out[q] = min(|{r : dist(q,r) <= thr}|, 100) / 100   (top-k unnecessary:
// any distance <= thr is among the 100 smallest unless count > 100, which clamps)
//
// Q=4096, R=16384, D=128. hit <=> dot(q,r) >= 0.5|q|^2 + (0.5|r|^2 - 0.5 thr^2)
// dist: 512-thread blocks (8 waves x 64 q-rows), grid (64 seg, 8 tileM) = 512
// blocks = 2/CU (the R8-proven low-FETCH shape) but 16 waves/CU = 4 waves/SIMD
// (the R9-proven TLP). 32x32x16 MFMA, BN=32, depth-3 LDS ring, counted vmcnt.

#define DIM   128
#define ROWB  256              // bytes per bf16 row
#define BM    512              // queries per block (8 waves x 64)
#define BN    32               // refs per round
#define NSEG  64               // segments along R (256 refs each)

typedef __attribute__((ext_vector_type(8)))  short short8;
typedef __attribute__((ext_vector_type(16))) float f32x16;

#define VMCNT(n) asm volatile("s_waitcnt vmcnt(" #n ")" ::: "memory")

// ---------------- prep: bf16 cast, folded norms/bias, zero counts ----------
__global__ void prep_kernel(const float* __restrict__ qe, const float* __restrict__ re,
                            __hip_bfloat16* __restrict__ qb, __hip_bfloat16* __restrict__ rb,
                            float* __restrict__ qhalf, float* __restrict__ rbias,
                            float* __restrict__ counts, const float* __restrict__ thr_p,
                            int Q, int R) {
    const int wave = threadIdx.x >> 6;
    const int lane = threadIdx.x & 63;
    const int row = blockIdx.x * 4 + wave;
    if (row >= Q + R) return;
    const float* src;
    __hip_bfloat16* dst;
    if (row < Q) {
        src = qe + (size_t)row * DIM;
        dst = qb + (size_t)row * DIM;
        if (lane == 0) counts[row] = 0.0f;
    } else {
        src = re + (size_t)(row - Q) * DIM;
        dst = rb + (size_t)(row - Q) * DIM;
    }
    float2 v = ((const float2*)src)[lane];
    float s = v.x * v.x + v.y * v.y;
    __hip_bfloat162 b;
    b.x = __float2bfloat16(v.x);
    b.y = __float2bfloat16(v.y);
    ((__hip_bfloat162*)dst)[lane] = b;
    #pragma unroll
    for (int off = 32; off > 0; off >>= 1) s += __shfl_down(s, off);
    if (lane == 0) {
        if (row < Q) qhalf[row] = 0.5f * s;
        else {
            const float thr = *thr_p;
            rbias[row - Q] = (thr >= 0.0f) ? 0.5f * s - 0.5f * thr * thr : 1e30f;
        }
    }
}

// ---------------- main: 8-wave blocks, 32x32x16 MFMA, depth-3 ring ---------
__launch_bounds__(512, 4)
__global__ void dist_count_kernel(const __hip_bfloat16* __restrict__ qb,
                                  const __hip_bfloat16* __restrict__ rb,
                                  const float* __restrict__ qhalf,
                                  const float* __restrict__ rbias,
                                  float* __restrict__ counts,
                                  int Q, int R) {
    __shared__ short Bs[3][BN * DIM];          // 3 x 8KB ring

    const int tid  = threadIdx.x;
    const int lane = tid & 63;
    const int wave = tid >> 6;                 // 0..7
    const int l31  = lane & 31;
    const int lhi  = lane >> 5;

    const int seg  = R / NSEG;                 // 256
    const int base = blockIdx.x * seg;
    const int tileM = blockIdx.y;
    const int NT   = seg / BN;                 // 8
    const int qrow0 = tileM * BM + wave * 64;

    const char* qbc = (const char*)qb;
    const char* rbc = (const char*)rb;

    // stage one 32x128 bf16 tile (8KB): 1 KB per wave (one 16B load/lane).
    // Linear LDS dest (required by global_load_lds); XOR-swizzle folded into
    // the GLOBAL source column (rule #21: both-sides-or-neither).
    auto stage = [&](int tt) {
        short* buf = Bs[tt % 3];
        const int lds_byte = wave * 1024 + lane * 16;
        const int row = lds_byte >> 8;         // 0..31
        const int col = lds_byte & 255;
        const int src = (base + tt * BN + row) * ROWB + (col ^ ((row & 15) << 4));
        __builtin_amdgcn_global_load_lds(
            (const __attribute__((address_space(1))) unsigned int*)(rbc + src),
            (__attribute__((address_space(3))) unsigned int*)((char*)buf + lds_byte),
            16, 0, 0);
    };

    // A fragments: 64 query rows x K=128 (32x32x16 layout: row=l31, k=lhi*8+j)
    short8 a[8][2];                            // 64 regs (unified VGPR/AGPR file)
    #pragma unroll
    for (int ks = 0; ks < 8; ++ks)
        #pragma unroll
        for (int mi = 0; mi < 2; ++mi)
            a[ks][mi] = *(const short8*)(qbc + (size_t)(qrow0 + mi * 32 + l31) * ROWB
                                         + ks * 32 + lhi * 16);

    // wave-level min of its 64 query half-norms (conservative screen bound)
    float minqh;
    {
        float mq = qhalf[qrow0 + lane];
        #pragma unroll
        for (int off = 32; off > 0; off >>= 1) mq = fminf(mq, __shfl_xor(mq, off));
        minqh = mq;
    }

    // per-tile rbias for this lane (8 rounds)
    float rbv[8];
    #pragma unroll
    for (int i = 0; i < 8; ++i) rbv[i] = rbias[base + i * BN + l31];

    stage(0);
    stage(1);
    VMCNT(1);                                  // my tile-0 load done

    for (int t = 0; t < NT; ++t) {
        __builtin_amdgcn_s_barrier();          // all waves' tile-t loads confirmed
        __builtin_amdgcn_sched_barrier(0);
        if (t + 2 < NT) stage(t + 2);          // slot (t+2)%3 free since round t-1

        const char* cur = (const char*)Bs[t % 3];
        f32x16 acc[2] = {};

        __builtin_amdgcn_s_setprio(1);
        #pragma unroll
        for (int ks = 0; ks < 8; ++ks) {
            const int cb = (ks * 32 + lhi * 16) ^ ((l31 & 15) << 4);
            const short8 b = *(const short8*)(cur + l31 * ROWB + cb);
            #pragma unroll
            for (int mi = 0; mi < 2; ++mi)
                acc[mi] = __builtin_amdgcn_mfma_f32_32x32x16_bf16(a[ks][mi], b, acc[mi], 0, 0, 0);
        }
        __builtin_amdgcn_s_setprio(0);

        // ---- screened epilogue ----
        const float rb_t = rbv[t];
        float mx = fmaxf(acc[0][0], acc[1][0]);
        #pragma unroll
        for (int r = 1; r < 16; ++r) mx = fmaxf(mx, fmaxf(acc[0][r], acc[1][r]));

        if (__any(mx >= minqh + rb_t)) {       // rare slow path (generic-correct)
            #pragma unroll
            for (int mi = 0; mi < 2; ++mi)
                #pragma unroll
                for (int reg = 0; reg < 16; ++reg) {
                    // 32x32 C layout: row = (reg&3) + 8*(reg>>2) + 4*lhi
                    const int row = qrow0 + mi * 32 + (reg & 3) + 8 * (reg >> 2) + 4 * lhi;
                    float cnt = (acc[mi][reg] >= qhalf[row] + rb_t) ? 1.0f : 0.0f;
                    cnt += __shfl_xor(cnt, 1);
                    cnt += __shfl_xor(cnt, 2);
                    cnt += __shfl_xor(cnt, 4);
                    cnt += __shfl_xor(cnt, 8);
                    cnt += __shfl_xor(cnt, 16);
                    if (l31 == 0 && cnt != 0.0f)
                        atomicAdd(&counts[row], cnt);
                }
        }

        if (t + 2 < NT) { VMCNT(1); }          // my t+1 load done; t+2 in flight
        else            { VMCNT(0); }
    }
}

// ---------------- finalize ----------------
__global__ void finalize_kernel(const float* __restrict__ counts,
                                float* __restrict__ out, int Q, int R) {
    int q = blockIdx.x * blockDim.x + threadIdx.x;
    if (q < Q) {
        float k = (R < 100) ? (float)R : 100.0f;
        out[q] = fminf(counts[q], k) / k;
    }
}

extern "C" void kernel_launch(void* const* d_in, const int* in_sizes, int n_in,
                              void* d_out, int out_size, void* d_ws, size_t ws_size,
                              hipStream_t stream) {
    const float* qe  = (const float*)d_in[0];
    const float* re  = (const float*)d_in[1];
    const float* thr = (const float*)d_in[2];
    float* out = (float*)d_out;

    const int Q = in_sizes[0] / DIM;   // 4096
    const int R = in_sizes[1] / DIM;   // 16384

    char* ws = (char*)d_ws;
    __hip_bfloat16* qb = (__hip_bfloat16*)ws;
    __hip_bfloat16* rb = (__hip_bfloat16*)(ws + (size_t)Q * DIM * 2);
    float* qhalf  = (float*)(ws + (size_t)(Q + R) * DIM * 2);
    float* rbias  = qhalf + Q;
    float* counts = rbias + R;

    const int rows = Q + R;
    prep_kernel<<<(rows + 3) / 4, 256, 0, stream>>>(qe, re, qb, rb, qhalf, rbias,
                                                    counts, thr, Q, R);

    dim3 grid(NSEG, Q / BM);           // (64, 8) = 512 blocks = 2/CU
    dist_count_kernel<<<grid, 512, 0, stream>>>(qb, rb, qhalf, rbias, counts, Q, R);

    finalize_kernel<<<(Q + 255) / 256, 256, 0, stream>>>(counts, out, Q, R);
}

// Round 12
// 31.518 us; speedup vs baseline: 2.2588x; 2.2550x over previous
//
#include <hip/hip_runtime.h>
#include <hip/hip_bf16.h>

// out[q] = min(|{r : dist(q,r) <= thr}|, 100) / 100   (top-k unnecessary:
// any distance <= thr is among the 100 smallest unless count > 100, which clamps)
//
// Q=4096, R=16384, D=128. hit <=> dot(q,r) >= 0.5|q|^2 + (0.5|r|^2 - 0.5 thr^2)
// dist: the R6-proven shape (best measured total): 256-thread blocks, 4 waves
// x 128 q-rows, BM=512, BN=32, 32x32x16 MFMA, depth-3 LDS ring, counted vmcnt,
// launch_bounds(256,2) / VGPR~128 (keeps HW block-packing low -> L2-resident;
// 64-VGPR variants let HW co-schedule more blocks and thrash L2: FETCH 8 MB
// -> 150 MB, measured R9/R10/R11). Screen uses per-lane rbias (exact per col).

#define DIM   128
#define ROWB  256              // bytes per bf16 row
#define BM    512              // queries per block (4 waves x 128)
#define BN    32               // refs per round
#define NSEG  64               // segments along R (256 refs each)

typedef __attribute__((ext_vector_type(8)))  short short8;
typedef __attribute__((ext_vector_type(16))) float f32x16;

#define VMCNT(n) asm volatile("s_waitcnt vmcnt(" #n ")" ::: "memory")

// ---------------- prep: bf16 cast, folded norms/bias, zero counts ----------
__global__ void prep_kernel(const float* __restrict__ qe, const float* __restrict__ re,
                            __hip_bfloat16* __restrict__ qb, __hip_bfloat16* __restrict__ rb,
                            float* __restrict__ qhalf, float* __restrict__ rbias,
                            float* __restrict__ counts, const float* __restrict__ thr_p,
                            int Q, int R) {
    const int wave = threadIdx.x >> 6;
    const int lane = threadIdx.x & 63;
    const int row = blockIdx.x * 4 + wave;
    if (row >= Q + R) return;
    const float* src;
    __hip_bfloat16* dst;
    if (row < Q) {
        src = qe + (size_t)row * DIM;
        dst = qb + (size_t)row * DIM;
        if (lane == 0) counts[row] = 0.0f;
    } else {
        src = re + (size_t)(row - Q) * DIM;
        dst = rb + (size_t)(row - Q) * DIM;
    }
    float2 v = ((const float2*)src)[lane];
    float s = v.x * v.x + v.y * v.y;
    __hip_bfloat162 b;
    b.x = __float2bfloat16(v.x);
    b.y = __float2bfloat16(v.y);
    ((__hip_bfloat162*)dst)[lane] = b;
    #pragma unroll
    for (int off = 32; off > 0; off >>= 1) s += __shfl_down(s, off);
    if (lane == 0) {
        if (row < Q) qhalf[row] = 0.5f * s;
        else {
            const float thr = *thr_p;
            rbias[row - Q] = (thr >= 0.0f) ? 0.5f * s - 0.5f * thr * thr : 1e30f;
        }
    }
}

// ---------------- main: 32x32x16 MFMA, depth-3 ring (R6 shape) -------------
__launch_bounds__(256, 2)
__global__ void dist_count_kernel(const __hip_bfloat16* __restrict__ qb,
                                  const __hip_bfloat16* __restrict__ rb,
                                  const float* __restrict__ qhalf,
                                  const float* __restrict__ rbias,
                                  float* __restrict__ counts,
                                  int Q, int R) {
    __shared__ short Bs[3][BN * DIM];          // 3 x 8KB ring

    const int tid  = threadIdx.x;
    const int lane = tid & 63;
    const int wave = tid >> 6;
    const int l31  = lane & 31;
    const int lhi  = lane >> 5;

    const int seg  = R / NSEG;                 // 256
    const int base = blockIdx.x * seg;
    const int tileM = blockIdx.y;
    const int NT   = seg / BN;                 // 8
    const int qrow0 = tileM * BM + wave * 128;

    const char* qbc = (const char*)qb;
    const char* rbc = (const char*)rb;

    // stage one 32x128 bf16 tile (8KB): linear LDS dest, XOR-swizzle folded
    // into the GLOBAL source column (rule #21: both-sides-or-neither).
    auto stage = [&](int tt) {
        short* buf = Bs[tt % 3];
        #pragma unroll
        for (int j = 0; j < 2; ++j) {
            const int lds_byte = (wave * 2 + j) * 1024 + lane * 16;
            const int row = lds_byte >> 8;     // 0..31
            const int col = lds_byte & 255;
            const int src = (base + tt * BN + row) * ROWB + (col ^ ((row & 15) << 4));
            __builtin_amdgcn_global_load_lds(
                (const __attribute__((address_space(1))) unsigned int*)(rbc + src),
                (__attribute__((address_space(3))) unsigned int*)((char*)buf + lds_byte),
                16, 0, 0);
        }
    };

    // A fragments: 128 query rows x K=128 (32x32x16 layout: row=l31, k=lhi*8+j)
    short8 a[8][4];                            // 128 VGPR
    #pragma unroll
    for (int ks = 0; ks < 8; ++ks)
        #pragma unroll
        for (int mi = 0; mi < 4; ++mi)
            a[ks][mi] = *(const short8*)(qbc + (size_t)(qrow0 + mi * 32 + l31) * ROWB
                                         + ks * 32 + lhi * 16);

    // wave-level min of the 128 query half-norms (conservative screen bound)
    float minqh;
    {
        float mq = fminf(qhalf[qrow0 + lane], qhalf[qrow0 + 64 + lane]);
        #pragma unroll
        for (int off = 32; off > 0; off >>= 1) mq = fminf(mq, __shfl_xor(mq, off));
        minqh = mq;
    }

    // per-tile rbias for this lane's column (8 rounds) — exact screen bound
    float rbv[8];
    #pragma unroll
    for (int i = 0; i < 8; ++i) rbv[i] = rbias[base + i * BN + l31];

    stage(0);
    stage(1);
    VMCNT(2);                                  // tile 0's loads (mine) done

    for (int t = 0; t < NT; ++t) {
        __builtin_amdgcn_s_barrier();          // all waves' tile-t loads confirmed
        __builtin_amdgcn_sched_barrier(0);
        if (t + 2 < NT) stage(t + 2);          // slot (t+2)%3 free since round t-1

        const char* cur = (const char*)Bs[t % 3];
        f32x16 acc[4] = {};                    // [mi]

        __builtin_amdgcn_s_setprio(1);
        #pragma unroll
        for (int ks = 0; ks < 8; ++ks) {
            // B layout: row(ref) = lane&31, k = (lane>>5)*8 + j
            const int cb = (ks * 32 + lhi * 16) ^ ((l31 & 15) << 4);
            const short8 b = *(const short8*)(cur + l31 * ROWB + cb);
            #pragma unroll
            for (int mi = 0; mi < 4; ++mi)
                acc[mi] = __builtin_amdgcn_mfma_f32_32x32x16_bf16(a[ks][mi], b, acc[mi], 0, 0, 0);
        }
        __builtin_amdgcn_s_setprio(0);

        // ---- screened epilogue (per-lane column bound, exact) ----
        const float rb_t = rbv[t];
        f32x16 m01 = acc[0], m23 = acc[2];
        #pragma unroll
        for (int r = 0; r < 16; ++r) {
            m01[r] = fmaxf(m01[r], acc[1][r]);
            m23[r] = fmaxf(m23[r], acc[3][r]);
        }
        float mx = fmaxf(m01[0], m23[0]);
        #pragma unroll
        for (int r = 1; r < 16; ++r) mx = fmaxf(mx, fmaxf(m01[r], m23[r]));

        if (__any(mx >= minqh + rb_t)) {       // rare slow path (generic-correct)
            #pragma unroll
            for (int mi = 0; mi < 4; ++mi)
                #pragma unroll
                for (int reg = 0; reg < 16; ++reg) {
                    // 32x32 C layout: row = (reg&3) + 8*(reg>>2) + 4*lhi
                    const int row = qrow0 + mi * 32 + (reg & 3) + 8 * (reg >> 2) + 4 * lhi;
                    float cnt = (acc[mi][reg] >= qhalf[row] + rb_t) ? 1.0f : 0.0f;
                    cnt += __shfl_xor(cnt, 1);
                    cnt += __shfl_xor(cnt, 2);
                    cnt += __shfl_xor(cnt, 4);
                    cnt += __shfl_xor(cnt, 8);
                    cnt += __shfl_xor(cnt, 16);
                    if (l31 == 0 && cnt != 0.0f)
                        atomicAdd(&counts[row], cnt);
                }
        }

        if (t + 2 < NT) { VMCNT(2); }          // tile t+1 resident; t+2 in flight
        else            { VMCNT(0); }
    }
}

// ---------------- finalize ----------------
__global__ void finalize_kernel(const float* __restrict__ counts,
                                float* __restrict__ out, int Q, int R) {
    int q = blockIdx.x * blockDim.x + threadIdx.x;
    if (q < Q) {
        float k = (R < 100) ? (float)R : 100.0f;
        out[q] = fminf(counts[q], k) / k;
    }
}

extern "C" void kernel_launch(void* const* d_in, const int* in_sizes, int n_in,
                              void* d_out, int out_size, void* d_ws, size_t ws_size,
                              hipStream_t stream) {
    const float* qe  = (const float*)d_in[0];
    const float* re  = (const float*)d_in[1];
    const float* thr = (const float*)d_in[2];
    float* out = (float*)d_out;

    const int Q = in_sizes[0] / DIM;   // 4096
    const int R = in_sizes[1] / DIM;   // 16384

    char* ws = (char*)d_ws;
    __hip_bfloat16* qb = (__hip_bfloat16*)ws;
    __hip_bfloat16* rb = (__hip_bfloat16*)(ws + (size_t)Q * DIM * 2);
    float* qhalf  = (float*)(ws + (size_t)(Q + R) * DIM * 2);
    float* rbias  = qhalf + Q;
    float* counts = rbias + R;

    const int rows = Q + R;
    prep_kernel<<<(rows + 3) / 4, 256, 0, stream>>>(qe, re, qb, rb, qhalf, rbias,
                                                    counts, thr, Q, R);

    dim3 grid(NSEG, Q / BM);           // (64, 8) = 512 blocks = 2/CU
    dist_count_kernel<<<grid, 256, 0, stream>>>(qb, rb, qhalf, rbias, counts, Q, R);

    finalize_kernel<<<(Q + 255) / 256, 256, 0, stream>>>(counts, out, Q, R);
}

// Round 13
// 31.180 us; speedup vs baseline: 2.2833x; 1.0108x over previous
//
#include <hip/hip_runtime.h>
#include <hip/hip_bf16.h>

// out[q] = min(|{r : dist(q,r) <= thr}|, 100) / 100   (top-k unnecessary:
// any distance <= thr is among the 100 smallest unless count > 100, which clamps)
//
// Q=4096, R=16384, D=128. hit <=> dot(q,r) >= 0.5|q|^2 + (0.5|r|^2 - 0.5 thr^2)
// dist: R12's frozen shape (256 thr, 4 waves x 128 q-rows, BM=512, VGPR~128,
// launch_bounds(256,2), grid (64,8) — the only shape measured FETCH~8MB), but
// TWO 32-ref tiles per barrier round on a 4-slot ring: barriers 8 -> 4.

#define DIM   128
#define ROWB  256              // bytes per bf16 row
#define BM    512              // queries per block (4 waves x 128)
#define BN    32               // refs per tile
#define NSEG  64               // segments along R (256 refs each)

typedef __attribute__((ext_vector_type(8)))  short short8;
typedef __attribute__((ext_vector_type(16))) float f32x16;

#define VMCNT(n) asm volatile("s_waitcnt vmcnt(" #n ")" ::: "memory")

// ---------------- prep: bf16 cast, folded norms/bias, zero counts ----------
__global__ void prep_kernel(const float* __restrict__ qe, const float* __restrict__ re,
                            __hip_bfloat16* __restrict__ qb, __hip_bfloat16* __restrict__ rb,
                            float* __restrict__ qhalf, float* __restrict__ rbias,
                            float* __restrict__ counts, const float* __restrict__ thr_p,
                            int Q, int R) {
    const int wave = threadIdx.x >> 6;
    const int lane = threadIdx.x & 63;
    const int row = blockIdx.x * 4 + wave;
    if (row >= Q + R) return;
    const float* src;
    __hip_bfloat16* dst;
    if (row < Q) {
        src = qe + (size_t)row * DIM;
        dst = qb + (size_t)row * DIM;
        if (lane == 0) counts[row] = 0.0f;
    } else {
        src = re + (size_t)(row - Q) * DIM;
        dst = rb + (size_t)(row - Q) * DIM;
    }
    float2 v = ((const float2*)src)[lane];
    float s = v.x * v.x + v.y * v.y;
    __hip_bfloat162 b;
    b.x = __float2bfloat16(v.x);
    b.y = __float2bfloat16(v.y);
    ((__hip_bfloat162*)dst)[lane] = b;
    #pragma unroll
    for (int off = 32; off > 0; off >>= 1) s += __shfl_down(s, off);
    if (lane == 0) {
        if (row < Q) qhalf[row] = 0.5f * s;
        else {
            const float thr = *thr_p;
            rbias[row - Q] = (thr >= 0.0f) ? 0.5f * s - 0.5f * thr * thr : 1e30f;
        }
    }
}

// ---------------- main: 32x32x16 MFMA, 4-slot ring, 2 tiles/barrier --------
__launch_bounds__(256, 2)
__global__ void dist_count_kernel(const __hip_bfloat16* __restrict__ qb,
                                  const __hip_bfloat16* __restrict__ rb,
                                  const float* __restrict__ qhalf,
                                  const float* __restrict__ rbias,
                                  float* __restrict__ counts,
                                  int Q, int R) {
    __shared__ short Bs[4][BN * DIM];          // 4 x 8KB ring

    const int tid  = threadIdx.x;
    const int lane = tid & 63;
    const int wave = tid >> 6;
    const int l31  = lane & 31;
    const int lhi  = lane >> 5;

    const int seg  = R / NSEG;                 // 256
    const int base = blockIdx.x * seg;
    const int tileM = blockIdx.y;
    const int NT   = seg / BN;                 // 8
    const int NP   = NT / 2;                   // 4 pair-rounds
    const int qrow0 = tileM * BM + wave * 128;

    const char* qbc = (const char*)qb;
    const char* rbc = (const char*)rb;

    // stage one 32x128 bf16 tile (8KB): linear LDS dest, XOR-swizzle folded
    // into the GLOBAL source column (rule #21: both-sides-or-neither).
    auto stage = [&](int tt) {
        short* buf = Bs[tt & 3];
        #pragma unroll
        for (int j = 0; j < 2; ++j) {
            const int lds_byte = (wave * 2 + j) * 1024 + lane * 16;
            const int row = lds_byte >> 8;     // 0..31
            const int col = lds_byte & 255;
            const int src = (base + tt * BN + row) * ROWB + (col ^ ((row & 15) << 4));
            __builtin_amdgcn_global_load_lds(
                (const __attribute__((address_space(1))) unsigned int*)(rbc + src),
                (__attribute__((address_space(3))) unsigned int*)((char*)buf + lds_byte),
                16, 0, 0);
        }
    };

    // A fragments: 128 query rows x K=128 (32x32x16 layout: row=l31, k=lhi*8+j)
    short8 a[8][4];                            // 128 VGPR
    #pragma unroll
    for (int ks = 0; ks < 8; ++ks)
        #pragma unroll
        for (int mi = 0; mi < 4; ++mi)
            a[ks][mi] = *(const short8*)(qbc + (size_t)(qrow0 + mi * 32 + l31) * ROWB
                                         + ks * 32 + lhi * 16);

    // wave-level min of the 128 query half-norms (conservative screen bound)
    float minqh;
    {
        float mq = fminf(qhalf[qrow0 + lane], qhalf[qrow0 + 64 + lane]);
        #pragma unroll
        for (int off = 32; off > 0; off >>= 1) mq = fminf(mq, __shfl_xor(mq, off));
        minqh = mq;
    }

    // per-tile rbias for this lane's column (8 tiles) — exact screen bound
    float rbv[8];
    #pragma unroll
    for (int i = 0; i < 8; ++i) rbv[i] = rbias[base + i * BN + l31];

    // one tile's compute + screened count (identical to R12's body)
    auto compute_tile = [&](int t) {
        const char* cur = (const char*)Bs[t & 3];
        f32x16 acc[4] = {};                    // [mi]

        __builtin_amdgcn_s_setprio(1);
        #pragma unroll
        for (int ks = 0; ks < 8; ++ks) {
            const int cb = (ks * 32 + lhi * 16) ^ ((l31 & 15) << 4);
            const short8 b = *(const short8*)(cur + l31 * ROWB + cb);
            #pragma unroll
            for (int mi = 0; mi < 4; ++mi)
                acc[mi] = __builtin_amdgcn_mfma_f32_32x32x16_bf16(a[ks][mi], b, acc[mi], 0, 0, 0);
        }
        __builtin_amdgcn_s_setprio(0);

        const float rb_t = rbv[t];
        f32x16 m01 = acc[0], m23 = acc[2];
        #pragma unroll
        for (int r = 0; r < 16; ++r) {
            m01[r] = fmaxf(m01[r], acc[1][r]);
            m23[r] = fmaxf(m23[r], acc[3][r]);
        }
        float mx = fmaxf(m01[0], m23[0]);
        #pragma unroll
        for (int r = 1; r < 16; ++r) mx = fmaxf(mx, fmaxf(m01[r], m23[r]));

        if (__any(mx >= minqh + rb_t)) {       // rare slow path (generic-correct)
            #pragma unroll
            for (int mi = 0; mi < 4; ++mi)
                #pragma unroll
                for (int reg = 0; reg < 16; ++reg) {
                    // 32x32 C layout: row = (reg&3) + 8*(reg>>2) + 4*lhi
                    const int row = qrow0 + mi * 32 + (reg & 3) + 8 * (reg >> 2) + 4 * lhi;
                    float cnt = (acc[mi][reg] >= qhalf[row] + rb_t) ? 1.0f : 0.0f;
                    cnt += __shfl_xor(cnt, 1);
                    cnt += __shfl_xor(cnt, 2);
                    cnt += __shfl_xor(cnt, 4);
                    cnt += __shfl_xor(cnt, 8);
                    cnt += __shfl_xor(cnt, 16);
                    if (l31 == 0 && cnt != 0.0f)
                        atomicAdd(&counts[row], cnt);
                }
        }
    };

    // prologue: tiles 0,1 into slots 0,1
    stage(0);
    if (NT > 1) stage(1);
    VMCNT(0);

    for (int p = 0; p < NP; ++p) {
        __builtin_amdgcn_s_barrier();          // tiles 2p,2p+1 resident (all waves)
        __builtin_amdgcn_sched_barrier(0);
        // slots (2p+2)&3,(2p+3)&3 were read in round p-1 -> free since barrier
        if (2 * p + 2 < NT) stage(2 * p + 2);
        if (2 * p + 3 < NT) stage(2 * p + 3);

        compute_tile(2 * p);
        if (2 * p + 1 < NT) compute_tile(2 * p + 1);

        VMCNT(0);                              // next pair staged (full round to fly)
    }
}

// ---------------- finalize ----------------
__global__ void finalize_kernel(const float* __restrict__ counts,
                                float* __restrict__ out, int Q, int R) {
    int q = blockIdx.x * blockDim.x + threadIdx.x;
    if (q < Q) {
        float k = (R < 100) ? (float)R : 100.0f;
        out[q] = fminf(counts[q], k) / k;
    }
}

extern "C" void kernel_launch(void* const* d_in, const int* in_sizes, int n_in,
                              void* d_out, int out_size, void* d_ws, size_t ws_size,
                              hipStream_t stream) {
    const float* qe  = (const float*)d_in[0];
    const float* re  = (const float*)d_in[1];
    const float* thr = (const float*)d_in[2];
    float* out = (float*)d_out;

    const int Q = in_sizes[0] / DIM;   // 4096
    const int R = in_sizes[1] / DIM;   // 16384

    char* ws = (char*)d_ws;
    __hip_bfloat16* qb = (__hip_bfloat16*)ws;
    __hip_bfloat16* rb = (__hip_bfloat16*)(ws + (size_t)Q * DIM * 2);
    float* qhalf  = (float*)(ws + (size_t)(Q + R) * DIM * 2);
    float* rbias  = qhalf + Q;
    float* counts = rbias + R;

    const int rows = Q + R;
    prep_kernel<<<(rows + 3) / 4, 256, 0, stream>>>(qe, re, qb, rb, qhalf, rbias,
                                                    counts, thr, Q, R);

    dim3 grid(NSEG, Q / BM);           // (64, 8) = 512 blocks = 2/CU
    dist_count_kernel<<<grid, 256, 0, stream>>>(qb, rb, qhalf, rbias, counts, Q, R);

    finalize_kernel<<<(Q + 255) / 256, 256, 0, stream>>>(counts, out, Q, R);
}